// Round 1
// baseline (343.486 us; speedup 1.0000x reference)
//
#include <hip/hip_runtime.h>
#include <cstdint>
#include <cstddef>

typedef unsigned short u16;
typedef short bf16x8 __attribute__((ext_vector_type(8)));
typedef float floatx4 __attribute__((ext_vector_type(4)));

#define GLD16(gp, sp) __builtin_amdgcn_global_load_lds(                      \
    (const __attribute__((address_space(1))) void*)(gp),                     \
    (__attribute__((address_space(3))) void*)(sp), 16, 0, 0)

__device__ __forceinline__ u16 f2bf(float f) {
  unsigned u = __float_as_uint(f);
  u += 0x7fffu + ((u >> 16) & 1u);   // round-to-nearest-even
  return (u16)(u >> 16);
}

// ---------------- conversions ----------------
__global__ void cvt_x_kernel(const float4* __restrict__ in, u16* __restrict__ out, int n4) {
  int i = blockIdx.x * blockDim.x + threadIdx.x;
  if (i >= n4) return;
  float4 v = in[i];
  ushort4 o;
  o.x = f2bf(v.x); o.y = f2bf(v.y); o.z = f2bf(v.z); o.w = f2bf(v.w);
  ((ushort4*)out)[i] = o;
}

// out[c][r] = bf16(in[r][c]); in is (R,C) f32, out is (C,R) bf16. z batches.
__global__ void transpose_cvt_kernel(const float* __restrict__ in, u16* __restrict__ out,
                                     int R, int C) {
  __shared__ float tile[32][33];
  size_t base = (size_t)blockIdx.z * (size_t)R * (size_t)C;
  int c0 = blockIdx.x * 32, r0 = blockIdx.y * 32;
  int tx = threadIdx.x, ty = threadIdx.y;  // 32 x 8
#pragma unroll
  for (int k = 0; k < 32; k += 8)
    tile[ty + k][tx] = in[base + (size_t)(r0 + ty + k) * C + (c0 + tx)];
  __syncthreads();
#pragma unroll
  for (int k = 0; k < 32; k += 8)
    out[base + (size_t)(c0 + ty + k) * R + (r0 + tx)] = f2bf(tile[tx][ty + k]);
}

// ---------------- router: logits -> softmax -> top2 ----------------
__global__ void router_kernel(const float* __restrict__ x, const float* __restrict__ rw,
                              const float* __restrict__ rb, float* __restrict__ ew,
                              float* __restrict__ combine) {
  const int t = blockIdx.x;
  const int lane = threadIdx.x;  // 64 threads = 1 wave
  const float4* xv = (const float4*)(x + (size_t)t * 1024);
  float acc[8];
#pragma unroll
  for (int e = 0; e < 8; ++e) acc[e] = 0.f;
  for (int j = lane; j < 256; j += 64) {
    float4 xx = xv[j];
#pragma unroll
    for (int e = 0; e < 8; ++e) {
      float4 wv = ((const float4*)(rw + (size_t)e * 1024))[j];
      acc[e] += xx.x * wv.x + xx.y * wv.y + xx.z * wv.z + xx.w * wv.w;
    }
  }
#pragma unroll
  for (int e = 0; e < 8; ++e) {
    float v = acc[e];
#pragma unroll
    for (int off = 32; off > 0; off >>= 1) v += __shfl_down(v, off);
    acc[e] = v;
  }
  if (lane == 0) {
    float p[8];
    float mx = -1e30f;
#pragma unroll
    for (int e = 0; e < 8; ++e) { p[e] = acc[e] + rb[e]; mx = fmaxf(mx, p[e]); }
    float sum = 0.f;
#pragma unroll
    for (int e = 0; e < 8; ++e) { p[e] = __expf(p[e] - mx); sum += p[e]; }
    float inv = 1.f / sum;
#pragma unroll
    for (int e = 0; e < 8; ++e) p[e] *= inv;
    // top-2, ties -> lower index (matches jax.lax.top_k)
    int i0 = 0;
#pragma unroll
    for (int e = 1; e < 8; ++e) if (p[e] > p[i0]) i0 = e;
    int i1 = (i0 == 0) ? 1 : 0;
#pragma unroll
    for (int e = 0; e < 8; ++e) if (e != i0 && e != i1 && p[e] > p[i1]) i1 = e;
    ew[t * 2 + 0] = p[i0];
    ew[t * 2 + 1] = p[i1];
#pragma unroll
    for (int e = 0; e < 8; ++e)
      combine[t * 8 + e] = (e == i0) ? p[i0] : ((e == i1) ? p[i1] : 0.f);
  }
}

// out[t,h] = sum_e combine[t,e] * w2_bias[e,h]   (also serves as the C-init for gemm2)
__global__ void bias_init_kernel(const float* __restrict__ combine, const float* __restrict__ w2b,
                                 float* __restrict__ out) {
  int idx = blockIdx.x * 256 + threadIdx.x;  // < 2048*1024
  int t = idx >> 10, h = idx & 1023;
  float s = 0.f;
#pragma unroll
  for (int e = 0; e < 8; ++e) s += combine[t * 8 + e] * w2b[e * 1024 + h];
  out[idx] = s;
}

// ---------------- shared 128x128xK bf16 GEMM core (m97-style) ----------------
// A: (M,K) row-major bf16. Bt: (N,K) row-major bf16. 256 thr = 4 waves (2x2 of 64x64).
__device__ __forceinline__ void gemm_block(
    const u16* __restrict__ A, int lda, const u16* __restrict__ Bt, int ldb,
    int rowBase, int colBase, int k0, int kIters,
    u16* As, u16* Bs, floatx4 acc[4][4]) {
  const int tid = threadIdx.x;
  const int lane = tid & 63;
  const int wave = tid >> 6;
  const int wr = wave >> 1, wc = wave & 1;
  const int sRow = lane >> 2;    // 0..15 within 16-row chunk
  const int sChunk = lane & 3;   // 16B chunk within 64B row
  const int fr = lane & 15;
  const int fq = lane >> 4;

#pragma unroll
  for (int mi = 0; mi < 4; ++mi)
#pragma unroll
    for (int ni = 0; ni < 4; ++ni)
      acc[mi][ni] = floatx4{0.f, 0.f, 0.f, 0.f};

  for (int kt = 0; kt < kIters; ++kt) {
    const int k = k0 + kt * 32;
    // stage A (128x32) and Bt (128x32) via async global->LDS, 16B/lane
#pragma unroll
    for (int r = 0; r < 2; ++r) {
      const int rl = (r * 4 + wave) * 16;  // wave-uniform 16-row chunk
      GLD16(A + (size_t)(rowBase + rl + sRow) * lda + k + sChunk * 8, As + rl * 32);
      GLD16(Bt + (size_t)(colBase + rl + sRow) * ldb + k + sChunk * 8, Bs + rl * 32);
    }
    __syncthreads();  // compiler emits vmcnt(0) drain before barrier
    bf16x8 af[4], bfr[4];
#pragma unroll
    for (int mi = 0; mi < 4; ++mi)
      af[mi] = *(const bf16x8*)(As + (wr * 64 + mi * 16 + fr) * 32 + fq * 8);
#pragma unroll
    for (int ni = 0; ni < 4; ++ni)
      bfr[ni] = *(const bf16x8*)(Bs + (wc * 64 + ni * 16 + fr) * 32 + fq * 8);
#pragma unroll
    for (int mi = 0; mi < 4; ++mi)
#pragma unroll
      for (int ni = 0; ni < 4; ++ni)
        acc[mi][ni] = __builtin_amdgcn_mfma_f32_16x16x32_bf16(af[mi], bfr[ni], acc[mi][ni], 0, 0, 0);
    __syncthreads();
  }
}

// GEMM1 + bias + clamp + glu + combine-scale -> actB bf16 (T x 8192), e-block layout
__global__ __launch_bounds__(256) void gemm1_act_kernel(
    const u16* __restrict__ xb, const u16* __restrict__ w1t,
    const float* __restrict__ w1b, const float* __restrict__ combine,
    u16* __restrict__ actB) {
  __shared__ __align__(16) u16 As[128 * 32];
  __shared__ __align__(16) u16 Bs[128 * 32];
  const int e = blockIdx.z;
  const int rowBase = blockIdx.x * 128;
  const int colBase = blockIdx.y * 128;
  floatx4 acc[4][4];
  gemm_block(xb, 1024, w1t + (size_t)e * 2048 * 1024, 1024, rowBase, colBase, 0, 32, As, Bs, acc);

  const int lane = threadIdx.x & 63;
  const int wave = threadIdx.x >> 6;
  const int wr = wave >> 1, wc = wave & 1;
  const int cl = lane & 15, ql = lane >> 4;
#pragma unroll
  for (int mi = 0; mi < 4; ++mi) {
#pragma unroll
    for (int r = 0; r < 4; ++r) {
      const int t = rowBase + wr * 64 + mi * 16 + ql * 4 + r;
      const float c = combine[t * 8 + e];
#pragma unroll
      for (int ni = 0; ni < 4; ++ni) {
        const int n = colBase + wc * 64 + ni * 16 + cl;   // interleaved col of w1
        float v = acc[mi][ni][r] + w1b[e * 2048 + n];
        float o = __shfl_xor(v, 1);                        // partner column
        if ((lane & 1) == 0) {                             // even lane = gate col (n even)
          float g = fminf(v, 7.f);
          float u = fminf(fmaxf(o, -7.f), 7.f);
          float sg = 1.f / (1.f + __expf(-1.702f * g));
          float a = (u + 1.f) * (g * sg);
          actB[(size_t)t * 8192 + e * 1024 + (n >> 1)] = f2bf(c * a);
        }
      }
    }
  }
}

// GEMM2: out += actB (2048x8192) @ w2t^T (8192x1024), split-K=4 via f32 atomics
__global__ __launch_bounds__(256) void gemm2_add_kernel(
    const u16* __restrict__ actB, const u16* __restrict__ w2t,
    float* __restrict__ out) {
  __shared__ __align__(16) u16 As[128 * 32];
  __shared__ __align__(16) u16 Bs[128 * 32];
  const int rowBase = blockIdx.x * 128;
  const int colBase = blockIdx.y * 128;
  const int k0 = blockIdx.z * 2048;
  floatx4 acc[4][4];
  gemm_block(actB, 8192, w2t, 8192, rowBase, colBase, k0, 64, As, Bs, acc);

  const int lane = threadIdx.x & 63;
  const int wave = threadIdx.x >> 6;
  const int wr = wave >> 1, wc = wave & 1;
  const int cl = lane & 15, ql = lane >> 4;
#pragma unroll
  for (int mi = 0; mi < 4; ++mi)
#pragma unroll
    for (int r = 0; r < 4; ++r) {
      const int t = rowBase + wr * 64 + mi * 16 + ql * 4 + r;
#pragma unroll
      for (int ni = 0; ni < 4; ++ni) {
        const int col = colBase + wc * 64 + ni * 16 + cl;
        atomicAdd(out + (size_t)t * 1024 + col, acc[mi][ni][r]);
      }
    }
}

extern "C" void kernel_launch(void* const* d_in, const int* in_sizes, int n_in,
                              void* d_out, int out_size, void* d_ws, size_t ws_size,
                              hipStream_t stream) {
  const float* x   = (const float*)d_in[0];   // (2048, 1024)
  const float* rw  = (const float*)d_in[1];   // (8, 1024)
  const float* rb  = (const float*)d_in[2];   // (8,)
  const float* w1  = (const float*)d_in[3];   // (8, 1024, 2048)
  const float* w1b = (const float*)d_in[4];   // (8, 2048)
  const float* w2  = (const float*)d_in[5];   // (8, 1024, 1024) -> flat (8192, 1024)
  const float* w2b = (const float*)d_in[6];   // (8, 1024)
  float* out = (float*)d_out;                 // 2048*1024
  float* ew  = out + (size_t)2048 * 1024;     // 2048*2

  char* ws = (char*)d_ws;
  float* combine = (float*)ws;                                   // 64 KiB (2048*8 f32)
  u16* xb   = (u16*)(ws + (64 << 10));                           // 4 MiB
  u16* w1t  = (u16*)(ws + (64 << 10) + (4ull << 20));            // 32 MiB  (E,2I,H)
  u16* w2t  = (u16*)(ws + (64 << 10) + (36ull << 20));           // 16 MiB  (H, E*I)
  u16* actB = (u16*)(ws + (64 << 10) + (52ull << 20));           // 32 MiB  (T, E*I)

  cvt_x_kernel<<<2048, 256, 0, stream>>>((const float4*)x, xb, 2048 * 1024 / 4);
  transpose_cvt_kernel<<<dim3(64, 32, 8), dim3(32, 8), 0, stream>>>(w1, w1t, 1024, 2048);
  transpose_cvt_kernel<<<dim3(32, 256, 1), dim3(32, 8), 0, stream>>>(w2, w2t, 8192, 1024);
  router_kernel<<<2048, 64, 0, stream>>>(x, rw, rb, ew, combine);
  bias_init_kernel<<<8192, 256, 0, stream>>>(combine, w2b, out);
  gemm1_act_kernel<<<dim3(16, 16, 8), 256, 0, stream>>>(xb, w1t, w1b, combine, actB);
  gemm2_add_kernel<<<dim3(16, 8, 4), 256, 0, stream>>>(actB, w2t, out);
}

// Round 2
// 271.399 us; speedup vs baseline: 1.2656x; 1.2656x over previous
//
#include <hip/hip_runtime.h>
#include <cstdint>
#include <cstddef>

typedef unsigned short u16;
typedef short bf16x8 __attribute__((ext_vector_type(8)));
typedef float floatx4 __attribute__((ext_vector_type(4)));

#define GLD16(gp, sp) __builtin_amdgcn_global_load_lds(                      \
    (const __attribute__((address_space(1))) void*)(gp),                     \
    (__attribute__((address_space(3))) void*)(sp), 16, 0, 0)

__device__ __forceinline__ u16 f2bf(float f) {
  unsigned u = __float_as_uint(f);
  u += 0x7fffu + ((u >> 16) & 1u);   // round-to-nearest-even
  return (u16)(u >> 16);
}

// ---------------- conversions ----------------
__global__ void cvt_x_kernel(const float4* __restrict__ in, u16* __restrict__ out, int n4) {
  int i = blockIdx.x * blockDim.x + threadIdx.x;
  if (i >= n4) return;
  float4 v = in[i];
  ushort4 o;
  o.x = f2bf(v.x); o.y = f2bf(v.y); o.z = f2bf(v.z); o.w = f2bf(v.w);
  ((ushort4*)out)[i] = o;
}

// out[c][r] = bf16(in[r][c]); in is (R,C) f32, out is (C,R) bf16. z batches (R*C each).
__global__ void transpose_cvt_kernel(const float* __restrict__ in, u16* __restrict__ out,
                                     int R, int C) {
  __shared__ float tile[32][33];
  size_t base = (size_t)blockIdx.z * (size_t)R * (size_t)C;
  int c0 = blockIdx.x * 32, r0 = blockIdx.y * 32;
  int tx = threadIdx.x, ty = threadIdx.y;  // 32 x 8
#pragma unroll
  for (int k = 0; k < 32; k += 8)
    tile[ty + k][tx] = in[base + (size_t)(r0 + ty + k) * C + (c0 + tx)];
  __syncthreads();
#pragma unroll
  for (int k = 0; k < 32; k += 8)
    out[base + (size_t)(c0 + ty + k) * R + (r0 + tx)] = f2bf(tile[tx][ty + k]);
}

// ---------------- router: logits -> softmax -> top2 (4 tokens/block) ----------------
__global__ void router_kernel(const float* __restrict__ x, const float* __restrict__ rw,
                              const float* __restrict__ rb, float* __restrict__ ew,
                              int* __restrict__ eids, float* __restrict__ eprobs) {
  const int wave = threadIdx.x >> 6, lane = threadIdx.x & 63;
  const int t = blockIdx.x * 4 + wave;
  const float4* xv = (const float4*)(x + (size_t)t * 1024);
  float acc[8];
#pragma unroll
  for (int e = 0; e < 8; ++e) acc[e] = 0.f;
  for (int j = lane; j < 256; j += 64) {
    float4 xx = xv[j];
#pragma unroll
    for (int e = 0; e < 8; ++e) {
      float4 wv = ((const float4*)(rw + (size_t)e * 1024))[j];
      acc[e] += xx.x * wv.x + xx.y * wv.y + xx.z * wv.z + xx.w * wv.w;
    }
  }
#pragma unroll
  for (int e = 0; e < 8; ++e) {
    float v = acc[e];
#pragma unroll
    for (int off = 32; off > 0; off >>= 1) v += __shfl_down(v, off);
    acc[e] = v;
  }
  if (lane == 0) {
    float p[8];
    float mx = -1e30f;
#pragma unroll
    for (int e = 0; e < 8; ++e) { p[e] = acc[e] + rb[e]; mx = fmaxf(mx, p[e]); }
    float sum = 0.f;
#pragma unroll
    for (int e = 0; e < 8; ++e) { p[e] = __expf(p[e] - mx); sum += p[e]; }
    float inv = 1.f / sum;
#pragma unroll
    for (int e = 0; e < 8; ++e) p[e] *= inv;
    int i0 = 0;
#pragma unroll
    for (int e = 1; e < 8; ++e) if (p[e] > p[i0]) i0 = e;
    int i1 = (i0 == 0) ? 1 : 0;
#pragma unroll
    for (int e = 0; e < 8; ++e) if (e != i0 && e != i1 && p[e] > p[i1]) i1 = e;
    ew[t * 2 + 0] = p[i0];
    ew[t * 2 + 1] = p[i1];
    eids[t * 2 + 0] = i0;
    eids[t * 2 + 1] = i1;
    eprobs[t * 2 + 0] = p[i0];
    eprobs[t * 2 + 1] = p[i1];
  }
}

// ---------------- build per-expert token lists + work list (1 block) ----------------
// meta[0]=nWork, meta[1..40]=(e<<8)|rowBlock, meta[48+e]=slotBase[e]
__global__ void build_lists_kernel(const int* __restrict__ eids, const float* __restrict__ eprobs,
                                   int* __restrict__ row_token, float* __restrict__ row_scale,
                                   int* __restrict__ meta) {
  __shared__ int cnt[8], base[8], cur[8];
  const int tid = threadIdx.x;
  if (tid < 8) { cnt[tid] = 0; cur[tid] = 0; }
  __syncthreads();
  for (int t = tid; t < 2048; t += 256) {
    atomicAdd(&cnt[eids[t * 2 + 0]], 1);
    atomicAdd(&cnt[eids[t * 2 + 1]], 1);
  }
  __syncthreads();
  if (tid == 0) {
    int off = 0, w = 0;
    for (int e = 0; e < 8; ++e) {
      base[e] = off;
      meta[48 + e] = off;
      int nb = (cnt[e] + 127) >> 7;
      for (int rb = 0; rb < nb; ++rb) meta[1 + w++] = (e << 8) | rb;
      off += nb << 7;
    }
    meta[0] = w;  // <= 39
  }
  __syncthreads();
  for (int s = tid; s < 5120; s += 256) { row_token[s] = -1; row_scale[s] = 0.f; }
  __syncthreads();
  for (int t = tid; t < 2048; t += 256) {
#pragma unroll
    for (int k = 0; k < 2; ++k) {
      int e = eids[t * 2 + k];
      int s = base[e] + atomicAdd(&cur[e], 1);
      row_token[s] = t;
      row_scale[s] = eprobs[t * 2 + k];
    }
  }
}

// out[t,h] = p0*w2b[e0,h] + p1*w2b[e1,h]  (C-init for gemm2)
__global__ void bias_init_kernel(const int* __restrict__ eids, const float* __restrict__ eprobs,
                                 const float* __restrict__ w2b, float* __restrict__ out) {
  int idx = blockIdx.x * 256 + threadIdx.x;  // < 2048*1024
  int t = idx >> 10, h = idx & 1023;
  int e0 = eids[t * 2], e1 = eids[t * 2 + 1];
  out[idx] = eprobs[t * 2] * w2b[e0 * 1024 + h] + eprobs[t * 2 + 1] * w2b[e1 * 1024 + h];
}

// ---------------- GEMM1 (gathered rows) + bias + glu + scale -> actS ----------------
// chunk-major LDS tile: group g (16 rows) at g*1024B, addr = g*1024 + (chunk*16+row)*16B
// frag read = base + lane*16B -> conflict-free ds_read_b128
__global__ __launch_bounds__(256) void gemm1_act_kernel(
    const u16* __restrict__ xb, const u16* __restrict__ w1t,
    const float* __restrict__ w1b,
    const int* __restrict__ row_token, const float* __restrict__ row_scale,
    const int* __restrict__ meta, u16* __restrict__ actS) {
  if ((int)blockIdx.x >= meta[0]) return;
  __shared__ __align__(16) u16 As[128 * 32];
  __shared__ __align__(16) u16 Bs[128 * 32];
  const int w = meta[1 + blockIdx.x];
  const int e = w >> 8, rb = w & 255;
  const int slotB = meta[48 + e] + rb * 128;
  const int colBase = blockIdx.y * 128;
  const int tid = threadIdx.x, lane = tid & 63, wave = tid >> 6;
  const int row16 = lane & 15, chunk = lane >> 4;
  const u16* Bt = w1t + (size_t)e * 2048 * 1024;
  const u16* aP[2]; const u16* bP[2];
#pragma unroll
  for (int r = 0; r < 2; ++r) {
    int g = r * 4 + wave;
    int tk = row_token[slotB + g * 16 + row16];
    if (tk < 0) tk = 0;
    aP[r] = xb + (size_t)tk * 1024 + chunk * 8;
    bP[r] = Bt + (size_t)(colBase + g * 16 + row16) * 1024 + chunk * 8;
  }
  const int wr = wave >> 1, wc = wave & 1;
  floatx4 acc[4][4];
#pragma unroll
  for (int mi = 0; mi < 4; ++mi)
#pragma unroll
    for (int ni = 0; ni < 4; ++ni) acc[mi][ni] = floatx4{0.f, 0.f, 0.f, 0.f};

  for (int kt = 0; kt < 32; ++kt) {
    const int k = kt * 32;
    GLD16(aP[0] + k, As + wave * 512);
    GLD16(bP[0] + k, Bs + wave * 512);
    GLD16(aP[1] + k, As + (4 + wave) * 512);
    GLD16(bP[1] + k, Bs + (4 + wave) * 512);
    __syncthreads();
    bf16x8 af[4], bfr[4];
#pragma unroll
    for (int mi = 0; mi < 4; ++mi) af[mi] = *(const bf16x8*)(As + (wr * 4 + mi) * 512 + lane * 8);
#pragma unroll
    for (int ni = 0; ni < 4; ++ni) bfr[ni] = *(const bf16x8*)(Bs + (wc * 4 + ni) * 512 + lane * 8);
#pragma unroll
    for (int mi = 0; mi < 4; ++mi)
#pragma unroll
      for (int ni = 0; ni < 4; ++ni)
        acc[mi][ni] = __builtin_amdgcn_mfma_f32_16x16x32_bf16(af[mi], bfr[ni], acc[mi][ni], 0, 0, 0);
    __syncthreads();
  }

  const int cl = lane & 15, ql = lane >> 4;
#pragma unroll
  for (int mi = 0; mi < 4; ++mi) {
#pragma unroll
    for (int r = 0; r < 4; ++r) {
      const int slot = slotB + wr * 64 + mi * 16 + ql * 4 + r;
      const float c = row_scale[slot];  // 0 for padded slots -> zero fill
#pragma unroll
      for (int ni = 0; ni < 4; ++ni) {
        const int n = colBase + wc * 64 + ni * 16 + cl;  // interleaved col of w1
        float v = acc[mi][ni][r] + w1b[e * 2048 + n];
        float o = __shfl_xor(v, 1);  // partner column
        if ((lane & 1) == 0) {       // even lane = gate col
          float g = fminf(v, 7.f);
          float u = fminf(fmaxf(o, -7.f), 7.f);
          float sg = 1.f / (1.f + __expf(-1.702f * g));
          float a = (u + 1.f) * (g * sg);
          actS[(size_t)slot * 1024 + (n >> 1)] = f2bf(c * a);
        }
      }
    }
  }
}

// ---------------- GEMM2: out[tok] += actS[slot] @ w2t[e]^T (atomic scatter) ----------------
__global__ __launch_bounds__(256) void gemm2_add_kernel(
    const u16* __restrict__ actS, const u16* __restrict__ w2t,
    const int* __restrict__ row_token, const int* __restrict__ meta,
    float* __restrict__ out) {
  if ((int)blockIdx.x >= meta[0]) return;
  __shared__ __align__(16) u16 As[128 * 32];
  __shared__ __align__(16) u16 Bs[128 * 32];
  const int w = meta[1 + blockIdx.x];
  const int e = w >> 8, rb = w & 255;
  const int slotB = meta[48 + e] + rb * 128;
  const int colBase = blockIdx.y * 128;
  const int tid = threadIdx.x, lane = tid & 63, wave = tid >> 6;
  const int row16 = lane & 15, chunk = lane >> 4;
  const u16* Bt = w2t + (size_t)e * 1024 * 1024;
  const u16* aP[2]; const u16* bP[2];
#pragma unroll
  for (int r = 0; r < 2; ++r) {
    int g = r * 4 + wave;
    aP[r] = actS + (size_t)(slotB + g * 16 + row16) * 1024 + chunk * 8;
    bP[r] = Bt + (size_t)(colBase + g * 16 + row16) * 1024 + chunk * 8;
  }
  const int wr = wave >> 1, wc = wave & 1;
  floatx4 acc[4][4];
#pragma unroll
  for (int mi = 0; mi < 4; ++mi)
#pragma unroll
    for (int ni = 0; ni < 4; ++ni) acc[mi][ni] = floatx4{0.f, 0.f, 0.f, 0.f};

  for (int kt = 0; kt < 32; ++kt) {
    const int k = kt * 32;
    GLD16(aP[0] + k, As + wave * 512);
    GLD16(bP[0] + k, Bs + wave * 512);
    GLD16(aP[1] + k, As + (4 + wave) * 512);
    GLD16(bP[1] + k, Bs + (4 + wave) * 512);
    __syncthreads();
    bf16x8 af[4], bfr[4];
#pragma unroll
    for (int mi = 0; mi < 4; ++mi) af[mi] = *(const bf16x8*)(As + (wr * 4 + mi) * 512 + lane * 8);
#pragma unroll
    for (int ni = 0; ni < 4; ++ni) bfr[ni] = *(const bf16x8*)(Bs + (wc * 4 + ni) * 512 + lane * 8);
#pragma unroll
    for (int mi = 0; mi < 4; ++mi)
#pragma unroll
      for (int ni = 0; ni < 4; ++ni)
        acc[mi][ni] = __builtin_amdgcn_mfma_f32_16x16x32_bf16(af[mi], bfr[ni], acc[mi][ni], 0, 0, 0);
    __syncthreads();
  }

  const int cl = lane & 15, ql = lane >> 4;
#pragma unroll
  for (int mi = 0; mi < 4; ++mi)
#pragma unroll
    for (int r = 0; r < 4; ++r) {
      const int slot = slotB + wr * 64 + mi * 16 + ql * 4 + r;
      const int tok = row_token[slot];
      if (tok < 0) continue;
#pragma unroll
      for (int ni = 0; ni < 4; ++ni) {
        const int col = colBase + wc * 64 + ni * 16 + cl;
        atomicAdd(out + (size_t)tok * 1024 + col, acc[mi][ni][r]);
      }
    }
}

extern "C" void kernel_launch(void* const* d_in, const int* in_sizes, int n_in,
                              void* d_out, int out_size, void* d_ws, size_t ws_size,
                              hipStream_t stream) {
  const float* x   = (const float*)d_in[0];   // (2048, 1024)
  const float* rw  = (const float*)d_in[1];   // (8, 1024)
  const float* rb  = (const float*)d_in[2];   // (8,)
  const float* w1  = (const float*)d_in[3];   // (8, 1024, 2048)
  const float* w1b = (const float*)d_in[4];   // (8, 2048)
  const float* w2  = (const float*)d_in[5];   // (8, 1024, 1024)
  const float* w2b = (const float*)d_in[6];   // (8, 1024)
  float* out = (float*)d_out;                 // 2048*1024
  float* ew  = out + (size_t)2048 * 1024;     // 2048*2

  char* ws = (char*)d_ws;
  u16* xb        = (u16*)(ws);                                   //  4 MiB
  u16* w1t       = (u16*)(ws + (4ull << 20));                    // 32 MiB  (E, 2I, H)
  u16* w2t       = (u16*)(ws + (36ull << 20));                   // 16 MiB  (E, H, I)
  u16* actS      = (u16*)(ws + (52ull << 20));                   // 10 MiB  (5120, 1024)
  int* eids      = (int*)(ws + (62ull << 20));                   // 16 KiB
  float* eprobs  = (float*)(ws + (62ull << 20) + (16 << 10));    // 16 KiB
  int* row_token = (int*)(ws + (62ull << 20) + (32 << 10));      // 20 KiB
  float* row_scale = (float*)(ws + (62ull << 20) + (52 << 10));  // 20 KiB
  int* meta      = (int*)(ws + (62ull << 20) + (72 << 10));      // 1 KiB

  cvt_x_kernel<<<2048, 256, 0, stream>>>((const float4*)x, xb, 2048 * 1024 / 4);
  transpose_cvt_kernel<<<dim3(64, 32, 8), dim3(32, 8), 0, stream>>>(w1, w1t, 1024, 2048);
  transpose_cvt_kernel<<<dim3(32, 32, 8), dim3(32, 8), 0, stream>>>(w2, w2t, 1024, 1024);
  router_kernel<<<512, 256, 0, stream>>>(x, rw, rb, ew, eids, eprobs);
  build_lists_kernel<<<1, 256, 0, stream>>>(eids, eprobs, row_token, row_scale, meta);
  bias_init_kernel<<<8192, 256, 0, stream>>>(eids, eprobs, w2b, out);
  gemm1_act_kernel<<<dim3(40, 16), 256, 0, stream>>>(xb, w1t, w1b, row_token, row_scale, meta, actS);
  gemm2_add_kernel<<<dim3(40, 8), 256, 0, stream>>>(actS, w2t, row_token, meta, out);
}